// Round 3
// baseline (201.563 us; speedup 1.0000x reference)
//
#include <hip/hip_runtime.h>

#define BB 32
#define NN 4096
#define NQ 8
#define DD 64
#define DV 64
#define CHUNKS 64
#define TOK_PER_BLOCK (NN / CHUNKS)      // 64
#define TOK_PER_WAVE (TOK_PER_BLOCK / 4) // 16

// Stage 1: each wave owns 16 tokens. Lane = m*8+g: m = query slot (0..7),
// g = dim octet (0..7). Q fragment lives in 8 regs/lane. Scores via per-lane
// FMA + xor(1,2,4) butterfly over g; softmax-sum over m via xor(8,16,32).
// No max-subtraction: scores are ~N(0,1) after the 1/8 scale (fp32-safe).
// Block-reduce 4 waves in LDS, then PLAIN coalesced stores of the per-block
// partial (520 floats) to a private workspace slice. NO global atomics —
// R2 showed 1M device-scope atomicAdds => 350 MB of HBM-side RMW traffic
// (WRITE_SIZE 188 MB) and waves stalled at vmcnt(0) (VALUBusy 6%).
__global__ __launch_bounds__(256, 8) void slot_attn_partial(
    const float* __restrict__ keys, const float* __restrict__ values,
    const float* __restrict__ query, float* __restrict__ PU, float* __restrict__ PS)
{
    const int b    = blockIdx.y;
    const int chnk = blockIdx.x;
    const int tid  = threadIdx.x;
    const int wave = tid >> 6;
    const int lane = tid & 63;
    const int m    = lane >> 3;
    const int g    = lane & 7;

    const float4* qp = (const float4*)(query + ((size_t)b * NQ + m) * DD + 8 * g);
    const float4 q0 = qp[0];
    const float4 q1 = qp[1];

    const float* Kb = keys   + (size_t)b * NN * DD;
    const float* Vb = values + (size_t)b * NN * DV;

    float u[8];
#pragma unroll
    for (int j = 0; j < 8; ++j) u[j] = 0.f;
    float s_acc = 0.f;

    const int tok0 = chnk * TOK_PER_BLOCK + wave * TOK_PER_WAVE;

    for (int t = tok0; t < tok0 + TOK_PER_WAVE; t += 4) {
        float4 k0[4], k1[4], v0[4], v1[4];
#pragma unroll
        for (int uu = 0; uu < 4; ++uu) {
            const float4* kp = (const float4*)(Kb + (size_t)(t + uu) * DD + 8 * g);
            const float4* vp = (const float4*)(Vb + (size_t)(t + uu) * DV + 8 * g);
            k0[uu] = kp[0]; k1[uu] = kp[1];
            v0[uu] = vp[0]; v1[uu] = vp[1];
        }
#pragma unroll
        for (int uu = 0; uu < 4; ++uu) {
            float s = k0[uu].x * q0.x + k0[uu].y * q0.y + k0[uu].z * q0.z + k0[uu].w * q0.w
                    + k1[uu].x * q1.x + k1[uu].y * q1.y + k1[uu].z * q1.z + k1[uu].w * q1.w;
            s += __shfl_xor(s, 1, 64);
            s += __shfl_xor(s, 2, 64);
            s += __shfl_xor(s, 4, 64);
            s *= 0.125f;  // 1/sqrt(64)
            float e = __expf(s);
            float sm = e;
            sm += __shfl_xor(sm, 8, 64);
            sm += __shfl_xor(sm, 16, 64);
            sm += __shfl_xor(sm, 32, 64);
            float alpha = e * __builtin_amdgcn_rcpf(sm) + 1e-8f;
            s_acc += alpha;
            u[0] += alpha * v0[uu].x;
            u[1] += alpha * v0[uu].y;
            u[2] += alpha * v0[uu].z;
            u[3] += alpha * v0[uu].w;
            u[4] += alpha * v1[uu].x;
            u[5] += alpha * v1[uu].y;
            u[6] += alpha * v1[uu].z;
            u[7] += alpha * v1[uu].w;
        }
    }

    // block-level reduction (4 waves) in LDS, then plain stores to partials
    __shared__ float lds[4 * 512];
    __shared__ float lds_s[4 * 8];
    float* dst = lds + wave * 512 + m * 64 + 8 * g;
#pragma unroll
    for (int j = 0; j < 8; ++j) dst[j] = u[j];
    if (g == 0) lds_s[wave * 8 + m] = s_acc;
    __syncthreads();

    float* pu = PU + ((size_t)b * CHUNKS + chnk) * 512;
#pragma unroll
    for (int o = 0; o < 2; ++o) {
        int idx = o * 256 + tid;
        pu[idx] = lds[idx] + lds[512 + idx] + lds[1024 + idx] + lds[1536 + idx];
    }
    if (tid < 8) {
        PS[((size_t)b * CHUNKS + chnk) * 8 + tid] =
            lds_s[tid] + lds_s[8 + tid] + lds_s[16 + tid] + lds_s[24 + tid];
    }
}

// Stage 2: out[b][m][v] = (sum_c PU[b][c][m*64+v]) / (sum_c PS[b][c][m])
// One block per batch; 512 threads = one per output element of that batch.
__global__ __launch_bounds__(512) void slot_attn_reduce(
    const float* __restrict__ PU, const float* __restrict__ PS,
    float* __restrict__ out)
{
    const int b = blockIdx.x;
    const int i = threadIdx.x;  // 0..511

    __shared__ float ssum[NQ];
    if (i < NQ) {
        float s = 0.f;
        const float* ps = PS + (size_t)b * CHUNKS * 8 + i;
#pragma unroll 8
        for (int c = 0; c < CHUNKS; ++c) s += ps[c * 8];
        ssum[i] = s;
    }
    __syncthreads();

    float usum = 0.f;
    const float* pu = PU + (size_t)b * CHUNKS * 512 + i;
#pragma unroll 8
    for (int c = 0; c < CHUNKS; ++c) usum += pu[c * 512];
    out[(size_t)b * 512 + i] = usum / ssum[i >> 6];
}

extern "C" void kernel_launch(void* const* d_in, const int* in_sizes, int n_in,
                              void* d_out, int out_size, void* d_ws, size_t ws_size,
                              hipStream_t stream) {
    const float* keys   = (const float*)d_in[0];
    const float* values = (const float*)d_in[1];
    const float* query  = (const float*)d_in[2];
    float* out = (float*)d_out;

    float* PU = (float*)d_ws;                       // BB*CHUNKS*512 = 4 MB
    float* PS = PU + (size_t)BB * CHUNKS * 512;     // BB*CHUNKS*8   = 64 KB

    slot_attn_partial<<<dim3(CHUNKS, BB), 256, 0, stream>>>(keys, values, query, PU, PS);
    slot_attn_reduce<<<dim3(BB), 512, 0, stream>>>(PU, PS, out);
}

// Round 4
// 120.098 us; speedup vs baseline: 1.6783x; 1.6783x over previous
//
#include <hip/hip_runtime.h>

#define BB 32
#define NN 4096
#define NQ 8
#define DD 64
#define DV 64
#define CHUNKS 16
#define TOK_PER_BLOCK (NN / CHUNKS)      // 256
#define TOK_PER_WAVE (TOK_PER_BLOCK / 4) // 64
#define BATCH 4
#define NBATCH (TOK_PER_WAVE / BATCH)    // 16

// Stage 1. Lane = m*8+g (m=slot, g=dim octet); Q fragment in 8 regs.
// Dot via 8 FMA + xor(1,2,4) butterfly; softmax-sum over m via xor(8,16,32)
// (no max-sub: scores ~N(0,1) after 1/8 scale, fp32-safe).
//
// KEY CHANGE vs R1-R3: explicit register double-buffering. R1-R3 compiled to
// VGPR_Count=32 -> the 16-load batch physically could not be in flight
// (needs 64 VGPRs of buffers) -> serialized load/wait/compute, exposed HBM
// latency dominated (VALUBusy 14%). Here: 2 batch buffers (32 float4 = 128
// VGPRs), issue batch i+1's loads BEFORE computing batch i, fully unrolled.
// CHUNKS=16 (512 blocks, 2 blocks/CU): grid caps us at 2 waves/SIMD anyway,
// so up to 512 VGPRs/wave are free -- spend them on in-flight loads.
// R2/R3's CHUNKS=64 regressed (55->118us) despite 83% occupancy: TLP can't
// fix a per-wave serialization problem, it just added per-block overhead.
__global__ __launch_bounds__(256, 2) void slot_attn_partial(
    const float* __restrict__ keys, const float* __restrict__ values,
    const float* __restrict__ query, float* __restrict__ PU, float* __restrict__ PS)
{
    const int b    = blockIdx.y;
    const int chnk = blockIdx.x;
    const int tid  = threadIdx.x;
    const int wave = tid >> 6;
    const int lane = tid & 63;
    const int m    = lane >> 3;
    const int g    = lane & 7;

    const float4* qp = (const float4*)(query + ((size_t)b * NQ + m) * DD + 8 * g);
    const float4 q0 = qp[0];
    const float4 q1 = qp[1];

    const float* Kbase = keys   + (size_t)b * NN * DD + 8 * g;
    const float* Vbase = values + (size_t)b * NN * DV + 8 * g;

    float u[8];
#pragma unroll
    for (int j = 0; j < 8; ++j) u[j] = 0.f;
    float s_acc = 0.f;

    const int tok0 = chnk * TOK_PER_BLOCK + wave * TOK_PER_WAVE;

    // double-buffered register batches: [buf][token-in-batch]
    float4 K0[2][BATCH], K1[2][BATCH], V0[2][BATCH], V1[2][BATCH];

    auto load_batch = [&](int buf, int t0) {
#pragma unroll
        for (int uu = 0; uu < BATCH; ++uu) {
            const float4* kp = (const float4*)(Kbase + (size_t)(t0 + uu) * DD);
            const float4* vp = (const float4*)(Vbase + (size_t)(t0 + uu) * DV);
            K0[buf][uu] = kp[0]; K1[buf][uu] = kp[1];
            V0[buf][uu] = vp[0]; V1[buf][uu] = vp[1];
        }
    };

    auto compute_batch = [&](int buf) {
#pragma unroll
        for (int uu = 0; uu < BATCH; ++uu) {
            const float4 k0 = K0[buf][uu], k1 = K1[buf][uu];
            float s = k0.x * q0.x + k0.y * q0.y + k0.z * q0.z + k0.w * q0.w
                    + k1.x * q1.x + k1.y * q1.y + k1.z * q1.z + k1.w * q1.w;
            s += __shfl_xor(s, 1, 64);
            s += __shfl_xor(s, 2, 64);
            s += __shfl_xor(s, 4, 64);
            s *= 0.125f;  // 1/sqrt(64)
            float e = __expf(s);
            float sm = e;
            sm += __shfl_xor(sm, 8, 64);
            sm += __shfl_xor(sm, 16, 64);
            sm += __shfl_xor(sm, 32, 64);
            const float alpha = e * __builtin_amdgcn_rcpf(sm) + 1e-8f;
            s_acc += alpha;
            const float4 v0 = V0[buf][uu], v1 = V1[buf][uu];
            u[0] += alpha * v0.x;
            u[1] += alpha * v0.y;
            u[2] += alpha * v0.z;
            u[3] += alpha * v0.w;
            u[4] += alpha * v1.x;
            u[5] += alpha * v1.y;
            u[6] += alpha * v1.z;
            u[7] += alpha * v1.w;
        }
    };

    load_batch(0, tok0);
#pragma unroll
    for (int i = 0; i < NBATCH; ++i) {
        const int cur = i & 1;
        if (i + 1 < NBATCH) load_batch(cur ^ 1, tok0 + (i + 1) * BATCH);
        compute_batch(cur);
    }

    // block-level reduction (4 waves) in LDS, then plain stores to partials
    __shared__ float lds[4 * 512];
    __shared__ float lds_s[4 * 8];
    float* dst = lds + wave * 512 + m * 64 + 8 * g;
#pragma unroll
    for (int j = 0; j < 8; ++j) dst[j] = u[j];
    if (g == 0) lds_s[wave * 8 + m] = s_acc;
    __syncthreads();

    float* pu = PU + ((size_t)b * CHUNKS + chnk) * 512;
#pragma unroll
    for (int o = 0; o < 2; ++o) {
        int idx = o * 256 + tid;
        pu[idx] = lds[idx] + lds[512 + idx] + lds[1024 + idx] + lds[1536 + idx];
    }
    if (tid < 8) {
        PS[((size_t)b * CHUNKS + chnk) * 8 + tid] =
            lds_s[tid] + lds_s[8 + tid] + lds_s[16 + tid] + lds_s[24 + tid];
    }
}

// Stage 2: out[b][m][v] = (sum_c PU[b][c][m*64+v]) / (sum_c PS[b][c][m])
__global__ __launch_bounds__(512) void slot_attn_reduce(
    const float* __restrict__ PU, const float* __restrict__ PS,
    float* __restrict__ out)
{
    const int b = blockIdx.x;
    const int i = threadIdx.x;  // 0..511

    __shared__ float ssum[NQ];
    if (i < NQ) {
        float s = 0.f;
        const float* ps = PS + (size_t)b * CHUNKS * 8 + i;
#pragma unroll
        for (int c = 0; c < CHUNKS; ++c) s += ps[c * 8];
        ssum[i] = s;
    }
    __syncthreads();

    float usum = 0.f;
    const float* pu = PU + (size_t)b * CHUNKS * 512 + i;
#pragma unroll
    for (int c = 0; c < CHUNKS; ++c) usum += pu[c * 512];
    out[(size_t)b * 512 + i] = usum / ssum[i >> 6];
}

extern "C" void kernel_launch(void* const* d_in, const int* in_sizes, int n_in,
                              void* d_out, int out_size, void* d_ws, size_t ws_size,
                              hipStream_t stream) {
    const float* keys   = (const float*)d_in[0];
    const float* values = (const float*)d_in[1];
    const float* query  = (const float*)d_in[2];
    float* out = (float*)d_out;

    float* PU = (float*)d_ws;                       // BB*CHUNKS*512 floats = 1 MB
    float* PS = PU + (size_t)BB * CHUNKS * 512;     // BB*CHUNKS*8 floats

    slot_attn_partial<<<dim3(CHUNKS, BB), 256, 0, stream>>>(keys, values, query, PU, PS);
    slot_attn_reduce<<<dim3(BB), 512, 0, stream>>>(PU, PS, out);
}

// Round 5
// 107.340 us; speedup vs baseline: 1.8778x; 1.1189x over previous
//
#include <hip/hip_runtime.h>

#define BB 32
#define NN 4096
#define NQ 8
#define DD 64
#define DV 64
#define CHUNKS 16
#define TOK_PER_BLOCK (NN / CHUNKS)      // 256
#define TOK_PER_WAVE (TOK_PER_BLOCK / 4) // 64
#define NGROUP (TOK_PER_WAVE / 8)        // 8 groups of 8 tokens

// Stage 1, (t,g) mapping: lane = t_sub*8 + g. Each lane loads K/V of ITS OWN
// token (t_sub within an 8-token group), dim octet g => ZERO load replication
// (R1-R4's (m,g) mapping had all 8 m-lanes loading the same 32B: 8x L1
// delivery, 256 load instr/wave). Each lane holds Q[m][8g..8g+7] for ALL m
// (64 VGPRs) and u[m][j] accumulators (64 VGPRs); softmax over m is
// in-register (no shuffles); only the g-reduction (xor 1,2,4) uses DS.
// Prefetch next group's 4 loads before computing current (reg double-buffer).
__global__ __launch_bounds__(256, 2) void slot_attn_partial(
    const float* __restrict__ keys, const float* __restrict__ values,
    const float* __restrict__ query, float* __restrict__ PU, float* __restrict__ PS)
{
    const int b     = blockIdx.y;
    const int chnk  = blockIdx.x;
    const int tid   = threadIdx.x;
    const int wave  = tid >> 6;
    const int lane  = tid & 63;
    const int t_sub = lane >> 3;  // token within group (0..7)
    const int g     = lane & 7;   // dim octet (0..7)

    // Q octet g for all 8 slots: 64 VGPRs
    float4 q0[8], q1[8];
    const float* qb = query + (size_t)b * NQ * DD + 8 * g;
#pragma unroll
    for (int m = 0; m < 8; ++m) {
        q0[m] = *(const float4*)(qb + m * DD);
        q1[m] = *(const float4*)(qb + m * DD + 4);
    }

    const float* Kbase = keys   + (size_t)b * NN * DD + 8 * g;
    const float* Vbase = values + (size_t)b * NN * DV + 8 * g;

    float u[8][8];
#pragma unroll
    for (int m = 0; m < 8; ++m)
#pragma unroll
        for (int j = 0; j < 8; ++j) u[m][j] = 0.f;
    float s_acc[8];
#pragma unroll
    for (int m = 0; m < 8; ++m) s_acc[m] = 0.f;

    const int tok0 = chnk * TOK_PER_BLOCK + wave * TOK_PER_WAVE;

    // current-group registers (this lane's token only: 16 floats K+V)
    const float4* kp = (const float4*)(Kbase + (size_t)(tok0 + t_sub) * DD);
    const float4* vp = (const float4*)(Vbase + (size_t)(tok0 + t_sub) * DV);
    float4 kc0 = kp[0], kc1 = kp[1], vc0 = vp[0], vc1 = vp[1];

#pragma unroll
    for (int i = 0; i < NGROUP; ++i) {
        float4 kn0, kn1, vn0, vn1;
        if (i + 1 < NGROUP) {  // prefetch next group
            const float4* kq = (const float4*)(Kbase + (size_t)(tok0 + 8 * (i + 1) + t_sub) * DD);
            const float4* vq = (const float4*)(Vbase + (size_t)(tok0 + 8 * (i + 1) + t_sub) * DV);
            kn0 = kq[0]; kn1 = kq[1]; vn0 = vq[0]; vn1 = vq[1];
        }

        // partial dots for this lane's token vs all 8 slots
        float s[8];
#pragma unroll
        for (int m = 0; m < 8; ++m) {
            s[m] = kc0.x * q0[m].x + kc0.y * q0[m].y + kc0.z * q0[m].z + kc0.w * q0[m].w
                 + kc1.x * q1[m].x + kc1.y * q1[m].y + kc1.z * q1[m].z + kc1.w * q1[m].w;
        }
        // reduce over g (lane bits 0..2); 8 independent chains -> DS latency hidden
#pragma unroll
        for (int m = 0; m < 8; ++m) {
            s[m] += __shfl_xor(s[m], 1, 64);
            s[m] += __shfl_xor(s[m], 2, 64);
            s[m] += __shfl_xor(s[m], 4, 64);
        }
        // softmax over m, fully in-register (no max-sub: scores ~N(0,1), fp32-safe)
        float e[8], sum = 0.f;
#pragma unroll
        for (int m = 0; m < 8; ++m) { e[m] = __expf(s[m] * 0.125f); sum += e[m]; }
        const float r = __builtin_amdgcn_rcpf(sum);
#pragma unroll
        for (int m = 0; m < 8; ++m) {
            const float a = e[m] * r + 1e-8f;
            s_acc[m] += a;
            u[m][0] += a * vc0.x; u[m][1] += a * vc0.y;
            u[m][2] += a * vc0.z; u[m][3] += a * vc0.w;
            u[m][4] += a * vc1.x; u[m][5] += a * vc1.y;
            u[m][6] += a * vc1.z; u[m][7] += a * vc1.w;
        }

        if (i + 1 < NGROUP) { kc0 = kn0; kc1 = kn1; vc0 = vn0; vc1 = vn1; }
    }

    // one-time reduction over t_sub (lane bits 3..5): 216 shuffles, ~0.5us
#pragma unroll
    for (int m = 0; m < 8; ++m) {
#pragma unroll
        for (int j = 0; j < 8; ++j) {
            u[m][j] += __shfl_xor(u[m][j], 8, 64);
            u[m][j] += __shfl_xor(u[m][j], 16, 64);
            u[m][j] += __shfl_xor(u[m][j], 32, 64);
        }
        s_acc[m] += __shfl_xor(s_acc[m], 8, 64);
        s_acc[m] += __shfl_xor(s_acc[m], 16, 64);
        s_acc[m] += __shfl_xor(s_acc[m], 32, 64);
    }

    __shared__ float lds[4 * 512];
    __shared__ float lds_s[4 * 8];
    if (t_sub == 0) {
        float* dst = lds + wave * 512 + 8 * g;
#pragma unroll
        for (int m = 0; m < 8; ++m)
#pragma unroll
            for (int j = 0; j < 8; ++j) dst[m * 64 + j] = u[m][j];
        if (g == 0) {
#pragma unroll
            for (int m = 0; m < 8; ++m) lds_s[wave * 8 + m] = s_acc[m];
        }
    }
    __syncthreads();

    float* pu = PU + ((size_t)b * CHUNKS + chnk) * 512;
#pragma unroll
    for (int o = 0; o < 2; ++o) {
        int idx = o * 256 + tid;
        pu[idx] = lds[idx] + lds[512 + idx] + lds[1024 + idx] + lds[1536 + idx];
    }
    if (tid < 8) {
        PS[((size_t)b * CHUNKS + chnk) * 8 + tid] =
            lds_s[tid] + lds_s[8 + tid] + lds_s[16 + tid] + lds_s[24 + tid];
    }
}

// Stage 2: out[b][m][v] = (sum_c PU[b][c][m*64+v]) / (sum_c PS[b][c][m])
__global__ __launch_bounds__(512) void slot_attn_reduce(
    const float* __restrict__ PU, const float* __restrict__ PS,
    float* __restrict__ out)
{
    const int b = blockIdx.x;
    const int i = threadIdx.x;  // 0..511

    __shared__ float ssum[NQ];
    if (i < NQ) {
        float s = 0.f;
        const float* ps = PS + (size_t)b * CHUNKS * 8 + i;
#pragma unroll
        for (int c = 0; c < CHUNKS; ++c) s += ps[c * 8];
        ssum[i] = s;
    }
    __syncthreads();

    float usum = 0.f;
    const float* pu = PU + (size_t)b * CHUNKS * 512 + i;
#pragma unroll
    for (int c = 0; c < CHUNKS; ++c) usum += pu[c * 512];
    out[(size_t)b * 512 + i] = usum / ssum[i >> 6];
}

extern "C" void kernel_launch(void* const* d_in, const int* in_sizes, int n_in,
                              void* d_out, int out_size, void* d_ws, size_t ws_size,
                              hipStream_t stream) {
    const float* keys   = (const float*)d_in[0];
    const float* values = (const float*)d_in[1];
    const float* query  = (const float*)d_in[2];
    float* out = (float*)d_out;

    float* PU = (float*)d_ws;                       // BB*CHUNKS*512 floats
    float* PS = PU + (size_t)BB * CHUNKS * 512;     // BB*CHUNKS*8 floats

    slot_attn_partial<<<dim3(CHUNKS, BB), 256, 0, stream>>>(keys, values, query, PU, PS);
    slot_attn_reduce<<<dim3(BB), 512, 0, stream>>>(PU, PS, out);
}

// Round 6
// 104.851 us; speedup vs baseline: 1.9224x; 1.0237x over previous
//
#include <hip/hip_runtime.h>

#define BB 32
#define NN 4096
#define NQ 8
#define DD 64
#define DV 64
#define CHUNKS 16
#define TOK_PER_BLOCK (NN / CHUNKS)      // 256
#define TOK_PER_WAVE (TOK_PER_BLOCK / 4) // 64
#define NGROUP (TOK_PER_WAVE / 8)        // 8 groups of 8 tokens

// Stage 1, (t,g) mapping: lane = t_sub*8 + g. Each lane loads K/V of ITS OWN
// token, dim octet g => zero load replication, fully coalesced. Each lane
// holds Q[m][octet g] for all 8 slots (64 VGPRs) and u[m][j] accumulators
// (64 VGPRs); softmax over m is in-register; only the g-reduction (xor 1,2,4)
// uses DS. R5 used depth-1 prefetch: ~560 cyc compute/group vs ~900 cyc load
// latency left ~340 cyc/group exposed with both waves stalling in lockstep.
// R6: depth-2 (triple-buffered) prefetch -- 2 groups of compute (~1120 cyc)
// between issue and first use covers latency even with no partner-wave help.
// Grid 512 blocks = 2/CU = 2 waves/SIMD; VGPR budget 512/wave, we use ~220.
__global__ __launch_bounds__(256, 2) void slot_attn_partial(
    const float* __restrict__ keys, const float* __restrict__ values,
    const float* __restrict__ query, float* __restrict__ PU, float* __restrict__ PS)
{
    const int b     = blockIdx.y;
    const int chnk  = blockIdx.x;
    const int tid   = threadIdx.x;
    const int wave  = tid >> 6;
    const int lane  = tid & 63;
    const int t_sub = lane >> 3;  // token within group (0..7)
    const int g     = lane & 7;   // dim octet (0..7)

    // Q octet g for all 8 slots: 64 VGPRs
    float4 q0[8], q1[8];
    const float* qb = query + (size_t)b * NQ * DD + 8 * g;
#pragma unroll
    for (int m = 0; m < 8; ++m) {
        q0[m] = *(const float4*)(qb + m * DD);
        q1[m] = *(const float4*)(qb + m * DD + 4);
    }

    const int tok0 = chnk * TOK_PER_BLOCK + wave * TOK_PER_WAVE;
    const float* Kbase = keys   + (size_t)b * NN * DD + (size_t)(tok0) * DD + 8 * g;
    const float* Vbase = values + (size_t)b * NN * DV + (size_t)(tok0) * DV + 8 * g;

    float u[8][8];
#pragma unroll
    for (int m = 0; m < 8; ++m)
#pragma unroll
        for (int j = 0; j < 8; ++j) u[m][j] = 0.f;
    float s_acc[8];
#pragma unroll
    for (int m = 0; m < 8; ++m) s_acc[m] = 0.f;

    // triple-buffered register batches (depth-2 prefetch)
    float4 kb0[3], kb1[3], vb0[3], vb1[3];

#pragma unroll
    for (int p = 0; p < 2; ++p) {  // preload groups 0,1
        const float4* kp = (const float4*)(Kbase + (size_t)(8 * p + t_sub) * DD);
        const float4* vp = (const float4*)(Vbase + (size_t)(8 * p + t_sub) * DV);
        kb0[p] = kp[0]; kb1[p] = kp[1]; vb0[p] = vp[0]; vb1[p] = vp[1];
    }

#pragma unroll
    for (int i = 0; i < NGROUP; ++i) {
        const int cur = i % 3;
        if (i + 2 < NGROUP) {  // prefetch group i+2
            const int nxt = (i + 2) % 3;
            const float4* kp = (const float4*)(Kbase + (size_t)(8 * (i + 2) + t_sub) * DD);
            const float4* vp = (const float4*)(Vbase + (size_t)(8 * (i + 2) + t_sub) * DV);
            kb0[nxt] = kp[0]; kb1[nxt] = kp[1]; vb0[nxt] = vp[0]; vb1[nxt] = vp[1];
        }

        const float4 kc0 = kb0[cur], kc1 = kb1[cur];
        // partial dots for this lane's token vs all 8 slots
        float s[8];
#pragma unroll
        for (int m = 0; m < 8; ++m) {
            s[m] = kc0.x * q0[m].x + kc0.y * q0[m].y + kc0.z * q0[m].z + kc0.w * q0[m].w
                 + kc1.x * q1[m].x + kc1.y * q1[m].y + kc1.z * q1[m].z + kc1.w * q1[m].w;
        }
        // reduce over g (lane bits 0..2); 8 independent chains
#pragma unroll
        for (int m = 0; m < 8; ++m) {
            s[m] += __shfl_xor(s[m], 1, 64);
            s[m] += __shfl_xor(s[m], 2, 64);
            s[m] += __shfl_xor(s[m], 4, 64);
        }
        // softmax over m, in-register (no max-sub: scores ~N(0,1), fp32-safe)
        float e[8], sum = 0.f;
#pragma unroll
        for (int m = 0; m < 8; ++m) { e[m] = __expf(s[m] * 0.125f); sum += e[m]; }
        const float r = __builtin_amdgcn_rcpf(sum);
        const float4 vc0 = vb0[cur], vc1 = vb1[cur];
#pragma unroll
        for (int m = 0; m < 8; ++m) {
            const float a = e[m] * r + 1e-8f;
            s_acc[m] += a;
            u[m][0] += a * vc0.x; u[m][1] += a * vc0.y;
            u[m][2] += a * vc0.z; u[m][3] += a * vc0.w;
            u[m][4] += a * vc1.x; u[m][5] += a * vc1.y;
            u[m][6] += a * vc1.z; u[m][7] += a * vc1.w;
        }
    }

    // one-time reduction over t_sub (lane bits 3..5)
#pragma unroll
    for (int m = 0; m < 8; ++m) {
#pragma unroll
        for (int j = 0; j < 8; ++j) {
            u[m][j] += __shfl_xor(u[m][j], 8, 64);
            u[m][j] += __shfl_xor(u[m][j], 16, 64);
            u[m][j] += __shfl_xor(u[m][j], 32, 64);
        }
        s_acc[m] += __shfl_xor(s_acc[m], 8, 64);
        s_acc[m] += __shfl_xor(s_acc[m], 16, 64);
        s_acc[m] += __shfl_xor(s_acc[m], 32, 64);
    }

    __shared__ float lds[4 * 512];
    __shared__ float lds_s[4 * 8];
    if (t_sub == 0) {
        float* dst = lds + wave * 512 + 8 * g;
#pragma unroll
        for (int m = 0; m < 8; ++m)
#pragma unroll
            for (int j = 0; j < 8; ++j) dst[m * 64 + j] = u[m][j];
        if (g == 0) {
#pragma unroll
            for (int m = 0; m < 8; ++m) lds_s[wave * 8 + m] = s_acc[m];
        }
    }
    __syncthreads();

    float* pu = PU + ((size_t)b * CHUNKS + chnk) * 512;
#pragma unroll
    for (int o = 0; o < 2; ++o) {
        int idx = o * 256 + tid;
        pu[idx] = lds[idx] + lds[512 + idx] + lds[1024 + idx] + lds[1536 + idx];
    }
    if (tid < 8) {
        PS[((size_t)b * CHUNKS + chnk) * 8 + tid] =
            lds_s[tid] + lds_s[8 + tid] + lds_s[16 + tid] + lds_s[24 + tid];
    }
}

// Stage 2: out[b][m][v] = (sum_c PU[b][c][m*64+v]) / (sum_c PS[b][c][m])
__global__ __launch_bounds__(512) void slot_attn_reduce(
    const float* __restrict__ PU, const float* __restrict__ PS,
    float* __restrict__ out)
{
    const int b = blockIdx.x;
    const int i = threadIdx.x;  // 0..511

    __shared__ float ssum[NQ];
    if (i < NQ) {
        float s = 0.f;
        const float* ps = PS + (size_t)b * CHUNKS * 8 + i;
#pragma unroll
        for (int c = 0; c < CHUNKS; ++c) s += ps[c * 8];
        ssum[i] = s;
    }
    __syncthreads();

    float usum = 0.f;
    const float* pu = PU + (size_t)b * CHUNKS * 512 + i;
#pragma unroll
    for (int c = 0; c < CHUNKS; ++c) usum += pu[c * 512];
    out[(size_t)b * 512 + i] = usum / ssum[i >> 6];
}

extern "C" void kernel_launch(void* const* d_in, const int* in_sizes, int n_in,
                              void* d_out, int out_size, void* d_ws, size_t ws_size,
                              hipStream_t stream) {
    const float* keys   = (const float*)d_in[0];
    const float* values = (const float*)d_in[1];
    const float* query  = (const float*)d_in[2];
    float* out = (float*)d_out;

    float* PU = (float*)d_ws;                       // BB*CHUNKS*512 floats
    float* PS = PU + (size_t)BB * CHUNKS * 512;     // BB*CHUNKS*8 floats

    slot_attn_partial<<<dim3(CHUNKS, BB), 256, 0, stream>>>(keys, values, query, PU, PS);
    slot_attn_reduce<<<dim3(BB), 512, 0, stream>>>(PU, PS, out);
}

// Round 7
// 99.452 us; speedup vs baseline: 2.0267x; 1.0543x over previous
//
#include <hip/hip_runtime.h>

#define BB 32
#define NN 4096
#define NQ 8
#define DD 64
#define DV 64
#define CHUNKS 16
#define TOK_PER_BLOCK (NN / CHUNKS)      // 256
#define TOK_PER_WAVE (TOK_PER_BLOCK / 4) // 64
#define NGROUP (TOK_PER_WAVE / 8)        // 8 groups of 8 tokens

// DPP cross-lane add on the VALU pipe (no DS instruction, ~2-4 cyc latency).
// R6 post-mortem: ~3300 ds_swizzle/CU from __shfl_xor was ~8us of DS-pipe
// occupancy + 3x ~30cyc serial latency per score group — the real stall.
template <int CTRL>
__device__ __forceinline__ float dpp_add(float x) {
    union { float f; int i; } in, out;
    in.f = x;
    out.i = __builtin_amdgcn_update_dpp(0, in.i, CTRL, 0xF, 0xF, true);
    return x + out.f;
}
// lane ^ 16 via ds_swizzle BitMode (within 32-lane halves: exact xor16)
__device__ __forceinline__ float swz16_add(float x) {
    union { float f; int i; } in, out;
    in.f = x;
    out.i = __builtin_amdgcn_ds_swizzle(in.i, 0x401F);
    return x + out.f;
}

// Stage 1, (t,g) mapping: lane = t_sub*8 + g. Each lane loads K/V of ITS OWN
// token, octet g => zero replication, coalesced. Q (pre-scaled by 1/8) for
// all 8 slots in 64 VGPRs; u[m][j] accumulators 64 VGPRs. Triple-buffered
// depth-2 register prefetch (R6 win). Score g-reduction via DPP only:
// xor1=quad_perm(1,0,3,2), xor2=quad_perm(2,3,0,1), then row_half_mirror
// (lane^7) which equals xor4 because values are quad-uniform at that point.
// Epilogue reduces t_sub bits 0,1 only (row_ror:8 DPP + ds_swizzle xor16);
// xor32 is skipped — each 32-lane half stores its own partial and the block
// reduce sums 8 partials instead of 4.
__global__ __launch_bounds__(256, 2) void slot_attn_partial(
    const float* __restrict__ keys, const float* __restrict__ values,
    const float* __restrict__ query, float* __restrict__ PU, float* __restrict__ PS)
{
    const int b     = blockIdx.y;
    const int chnk  = blockIdx.x;
    const int tid   = threadIdx.x;
    const int wave  = tid >> 6;
    const int lane  = tid & 63;
    const int t_sub = lane >> 3;  // token within group (0..7)
    const int g     = lane & 7;   // dim octet (0..7)

    // Q octet g for all 8 slots, pre-scaled by 1/sqrt(64)
    float4 q0[8], q1[8];
    const float* qb = query + (size_t)b * NQ * DD + 8 * g;
#pragma unroll
    for (int m = 0; m < 8; ++m) {
        float4 a = *(const float4*)(qb + m * DD);
        float4 c = *(const float4*)(qb + m * DD + 4);
        a.x *= 0.125f; a.y *= 0.125f; a.z *= 0.125f; a.w *= 0.125f;
        c.x *= 0.125f; c.y *= 0.125f; c.z *= 0.125f; c.w *= 0.125f;
        q0[m] = a; q1[m] = c;
    }

    const int tok0 = chnk * TOK_PER_BLOCK + wave * TOK_PER_WAVE;
    const float* Kbase = keys   + ((size_t)b * NN + tok0) * DD + 8 * g;
    const float* Vbase = values + ((size_t)b * NN + tok0) * DV + 8 * g;

    float u[8][8];
#pragma unroll
    for (int m = 0; m < 8; ++m)
#pragma unroll
        for (int j = 0; j < 8; ++j) u[m][j] = 0.f;
    float s_acc[8];
#pragma unroll
    for (int m = 0; m < 8; ++m) s_acc[m] = 0.f;

    // triple-buffered register batches (depth-2 prefetch)
    float4 kb0[3], kb1[3], vb0[3], vb1[3];
#pragma unroll
    for (int p = 0; p < 2; ++p) {
        const float4* kp = (const float4*)(Kbase + (size_t)(8 * p + t_sub) * DD);
        const float4* vp = (const float4*)(Vbase + (size_t)(8 * p + t_sub) * DV);
        kb0[p] = kp[0]; kb1[p] = kp[1]; vb0[p] = vp[0]; vb1[p] = vp[1];
    }

#pragma unroll
    for (int i = 0; i < NGROUP; ++i) {
        const int cur = i % 3;
        if (i + 2 < NGROUP) {
            const int nxt = (i + 2) % 3;
            const float4* kp = (const float4*)(Kbase + (size_t)(8 * (i + 2) + t_sub) * DD);
            const float4* vp = (const float4*)(Vbase + (size_t)(8 * (i + 2) + t_sub) * DV);
            kb0[nxt] = kp[0]; kb1[nxt] = kp[1]; vb0[nxt] = vp[0]; vb1[nxt] = vp[1];
        }

        const float4 kc0 = kb0[cur], kc1 = kb1[cur];
        float s[8];
#pragma unroll
        for (int m = 0; m < 8; ++m) {
            s[m] = kc0.x * q0[m].x + kc0.y * q0[m].y + kc0.z * q0[m].z + kc0.w * q0[m].w
                 + kc1.x * q1[m].x + kc1.y * q1[m].y + kc1.z * q1[m].z + kc1.w * q1[m].w;
        }
        // g-reduction entirely on VALU via DPP (no DS ops)
#pragma unroll
        for (int m = 0; m < 8; ++m) {
            s[m] = dpp_add<0xB1>(s[m]);   // + lane^1 (quad_perm 1,0,3,2)
            s[m] = dpp_add<0x4E>(s[m]);   // + lane^2 (quad_perm 2,3,0,1)
            s[m] = dpp_add<0x141>(s[m]);  // + lane^7 == xor4 (quad-uniform)
        }
        // softmax over m, in-register (no max-sub: scores ~N(0,1), fp32-safe)
        float e[8], sum = 0.f;
#pragma unroll
        for (int m = 0; m < 8; ++m) { e[m] = __expf(s[m]); sum += e[m]; }
        const float r = __builtin_amdgcn_rcpf(sum);
        const float4 vc0 = vb0[cur], vc1 = vb1[cur];
#pragma unroll
        for (int m = 0; m < 8; ++m) {
            const float a = e[m] * r + 1e-8f;
            s_acc[m] += a;
            u[m][0] += a * vc0.x; u[m][1] += a * vc0.y;
            u[m][2] += a * vc0.z; u[m][3] += a * vc0.w;
            u[m][4] += a * vc1.x; u[m][5] += a * vc1.y;
            u[m][6] += a * vc1.z; u[m][7] += a * vc1.w;
        }
    }

    // epilogue: reduce over t_sub bits 0,1 (lane^8 via DPP row_ror:8 — exact;
    // lane^16 via ds_swizzle). t_sub bit 2 (lane^32) handled by storing
    // per-half partials and widening the block reduce to 8 terms.
#pragma unroll
    for (int m = 0; m < 8; ++m) {
#pragma unroll
        for (int j = 0; j < 8; ++j) {
            u[m][j] = dpp_add<0x128>(u[m][j]);  // + lane^8 (row_ror:8)
            u[m][j] = swz16_add(u[m][j]);       // + lane^16
        }
        s_acc[m] = dpp_add<0x128>(s_acc[m]);
        s_acc[m] = swz16_add(s_acc[m]);
    }

    __shared__ float lds[8 * 512];
    __shared__ float lds_s[8 * 8];
    const int half = lane >> 5;
    if ((lane & 24) == 0) {  // lanes 0-7 and 32-39 hold the half-sums
        float* dst = lds + (wave * 2 + half) * 512 + 8 * g;
#pragma unroll
        for (int m = 0; m < 8; ++m)
#pragma unroll
            for (int j = 0; j < 8; ++j) dst[m * 64 + j] = u[m][j];
        if (g == 0) {
#pragma unroll
            for (int m = 0; m < 8; ++m) lds_s[(wave * 2 + half) * 8 + m] = s_acc[m];
        }
    }
    __syncthreads();

    float* pu = PU + ((size_t)b * CHUNKS + chnk) * 512;
#pragma unroll
    for (int o = 0; o < 2; ++o) {
        int idx = o * 256 + tid;
        float sum = 0.f;
#pragma unroll
        for (int k = 0; k < 8; ++k) sum += lds[k * 512 + idx];
        pu[idx] = sum;
    }
    if (tid < 8) {
        float ssum = 0.f;
#pragma unroll
        for (int k = 0; k < 8; ++k) ssum += lds_s[k * 8 + tid];
        PS[((size_t)b * CHUNKS + chnk) * 8 + tid] = ssum;
    }
}

// Stage 2: out[b][m][v] = (sum_c PU[b][c][m*64+v]) / (sum_c PS[b][c][m])
__global__ __launch_bounds__(512) void slot_attn_reduce(
    const float* __restrict__ PU, const float* __restrict__ PS,
    float* __restrict__ out)
{
    const int b = blockIdx.x;
    const int i = threadIdx.x;  // 0..511

    __shared__ float ssum[NQ];
    if (i < NQ) {
        float s = 0.f;
        const float* ps = PS + (size_t)b * CHUNKS * 8 + i;
#pragma unroll
        for (int c = 0; c < CHUNKS; ++c) s += ps[c * 8];
        ssum[i] = s;
    }
    __syncthreads();

    float usum = 0.f;
    const float* pu = PU + (size_t)b * CHUNKS * 512 + i;
#pragma unroll
    for (int c = 0; c < CHUNKS; ++c) usum += pu[c * 512];
    out[(size_t)b * 512 + i] = usum / ssum[i >> 6];
}

extern "C" void kernel_launch(void* const* d_in, const int* in_sizes, int n_in,
                              void* d_out, int out_size, void* d_ws, size_t ws_size,
                              hipStream_t stream) {
    const float* keys   = (const float*)d_in[0];
    const float* values = (const float*)d_in[1];
    const float* query  = (const float*)d_in[2];
    float* out = (float*)d_out;

    float* PU = (float*)d_ws;                       // BB*CHUNKS*512 floats
    float* PS = PU + (size_t)BB * CHUNKS * 512;     // BB*CHUNKS*8 floats

    slot_attn_partial<<<dim3(CHUNKS, BB), 256, 0, stream>>>(keys, values, query, PU, PS);
    slot_attn_reduce<<<dim3(BB), 512, 0, stream>>>(PU, PS, out);
}